// Round 5
// baseline (264.804 us; speedup 1.0000x reference)
//
#include <hip/hip_runtime.h>
#include <hip/hip_bf16.h>
#include <cstdint>

#define B_ 4
#define H_ 80
#define W_ 80
#define CH_ 256
#define NC_ 22
#define DIM_ 256
#define NPIX (B_*H_*W_)

typedef unsigned short ushort;
typedef __attribute__((ext_vector_type(8))) short short8;     // 8 bf16 = 4 VGPR
typedef __attribute__((ext_vector_type(4))) float floatx4;    // MFMA C/D frag

__device__ __attribute__((aligned(256))) static const unsigned char zglob[256] = {};

static __device__ inline ushort f2bf(float v) {
    __hip_bfloat16 h = __float2bfloat16(v);   // RNE
    ushort r;
    __builtin_memcpy(&r, &h, 2);
    return r;
}
static __device__ inline unsigned pk2(float a, float b) {
    return (unsigned)f2bf(a) | ((unsigned)f2bf(b) << 16);
}
static __device__ inline void gll16(const void* g, void* l) {
    __builtin_amdgcn_global_load_lds((const __attribute__((address_space(1))) void*)g,
                                     (__attribute__((address_space(3))) void*)l, 16, 0, 0);
}

// ---------------------------------------------------------------------------
// prep: fused {raw sel, (m,k)-parallel} + {weight repack} (r1-proven).
// ---------------------------------------------------------------------------
__global__ __launch_bounds__(256) void prep(const float* __restrict__ seg,
                                            const float* __restrict__ cw,
                                            float* __restrict__ ssel,
                                            ushort* __restrict__ wbT)
{
    __shared__ ushort ls[32][260];
    if (blockIdx.x < 900) {
        const int t = blockIdx.x * 256 + threadIdx.x;     // = k*NPIX + m
        const int k = t / NPIX;
        const int m = t - k * NPIX;
        const int w = m % W_;
        const int h = (m / W_) % H_;
        const int b = m / (W_ * H_);

        const float2* c2 = (const float2*)(seg + (size_t)m * NC_);
        float cv[NC_];
        #pragma unroll
        for (int c = 0; c < NC_ / 2; ++c) { float2 v = c2[c]; cv[2*c] = v.x; cv[2*c+1] = v.y; }
        float mx = -1e30f;
        #pragma unroll
        for (int c = 0; c < NC_; ++c) mx = fmaxf(mx, cv[c]);

        const int i = k / 3, j = k % 3;
        const int hh = h + i - 1, ww = w + j - 1;
        float s = 0.f;
        if (hh >= 0 && hh < H_ && ww >= 0 && ww < W_) {
            const float2* n2 = (const float2*)(seg + ((size_t)((b * H_ + hh) * W_ + ww)) * NC_);
            #pragma unroll
            for (int c = 0; c < NC_ / 2; ++c) {
                float2 v = n2[c];
                s += (cv[2*c]   == mx) ? v.x : 0.f;
                s += (cv[2*c+1] == mx) ? v.y : 0.f;
            }
        }
        ssel[t] = s;                                      // raw sel
    } else {
        const int bx = blockIdx.x - 900;
        const int k  = bx / 8;
        const int c0 = (bx % 8) * 32;
        const int c    = threadIdx.x >> 3;                // 0..31
        const int seg8 = threadIdx.x & 7;                 // 0..7

        const float* src = cw + ((size_t)(c0 + c) * 9 + k) * DIM_ + seg8 * 32;
        #pragma unroll
        for (int e = 0; e < 32; e += 4) {
            float4 v = *(const float4*)(src + e);
            unsigned* dst = (unsigned*)&ls[c][seg8 * 32 + e];
            dst[0] = pk2(v.x, v.y);
            dst[1] = pk2(v.z, v.w);
        }
        __syncthreads();

        const int d = threadIdx.x;                        // 0..255
        ushort tmp[32];
        #pragma unroll
        for (int cc = 0; cc < 32; ++cc) tmp[cc] = ls[cc][d];
        uint4 o[4];
        __builtin_memcpy(o, tmp, 64);
        uint4* dst = (uint4*)(wbT + ((size_t)k * 256 + d) * 256 + c0);
        dst[0] = o[0]; dst[1] = o[1]; dst[2] = o[2]; dst[3] = o[3];
    }
}

// ---------------------------------------------------------------------------
// cvt_x: x f32 -> xb bf16 (13 MB). 8 elems/thread.
// ---------------------------------------------------------------------------
__global__ __launch_bounds__(256) void cvt_x(const float* __restrict__ x,
                                             ushort* __restrict__ xb)
{
    size_t idx = ((size_t)blockIdx.x * 256 + threadIdx.x) * 8;
    const float4* s = (const float4*)(x + idx);
    float4 a = s[0], b = s[1];
    uint4 o = make_uint4(pk2(a.x, a.y), pk2(a.z, a.w), pk2(b.x, b.y), pk2(b.z, b.w));
    *(uint4*)(xb + idx) = o;
}

// ---------------------------------------------------------------------------
// conv2: barrier-light taps-outer implicit GEMM. 5 barriers/block total.
// LDS: one input row (82 px x 256 ch bf16, XOR-swizzled chunk^=p&7) staged
// via global_load_lds; per i-row: free-run 3 taps x 8 kk x (5im x 2jn MFMA).
// B: rgA/rgB half-tap double-ring, prefetched one tap ahead after last use;
// NOTHING else in flight during free-run -> no in-order-vmcnt poison.
// P im-group split (3+2) -> 64 acc regs; O += sl[k][m]*P after each group.
// ---------------------------------------------------------------------------
__global__ __launch_bounds__(256, 3) void conv2(const ushort* __restrict__ xb,
                                                const float* __restrict__ ssel,
                                                const ushort* __restrict__ wbT,
                                                float* __restrict__ out)
{
    __shared__ __attribute__((aligned(1024))) ushort xt[82 * 32 * 8];  // 41984 B
    __shared__ float sl[9][80];                                        // 2.8 KB

    const int tid  = threadIdx.x;
    const int lane = tid & 63;
    const int wv   = tid >> 6;
    const int ln   = lane & 15;
    const int quad = lane >> 4;
    const int rt   = blockIdx.x;             // b*H + h
    const int b    = rt / H_;
    const int h    = rt % H_;
    const int d0   = blockIdx.y * 128;

    const int Dbase = (d0 + wv * 32 + ln) * 256 + quad * 8;   // ushort units

    floatx4 O[5][2];
    #pragma unroll
    for (int i = 0; i < 5; ++i)
        #pragma unroll
        for (int jn = 0; jn < 2; ++jn)
            O[i][jn] = (floatx4){0.f, 0.f, 0.f, 0.f};

    short8 rgA[8], rgB[8];                    // B frags: kk-halves of one tap

    auto loadBh = [&](int k, int kh, short8* dst) {
        const ushort* bb = wbT + (size_t)k * 65536 + Dbase + kh * 128;
        #pragma unroll
        for (int k2 = 0; k2 < 4; ++k2)
            #pragma unroll
            for (int jn = 0; jn < 2; ++jn)
                dst[k2 * 2 + jn] = *(const short8*)(bb + k2 * 32 + jn * 4096);
    };

    // stage input row (h+ri-1) into xt. 41 x 1KB wave-chunks, swizzled source:
    // lds slot s (p=s>>5, cph=s&31) holds global chunk clog = cph ^ (p&7).
    auto stage_row = [&](int ri) {
        const int rr = h + ri - 1;
        const bool rowok = (rr >= 0) && (rr < H_);
        const ushort* xrow = xb + ((size_t)((b * H_ + (rowok ? rr : 0)) * W_)) * CH_;
        #pragma unroll
        for (int n = 0; n < 11; ++n) {
            const int e = wv + 4 * n;
            if (e < 41) {                     // wave-uniform guard
                const int slot = e * 64 + lane;
                const int p    = slot >> 5;   // 0..81 (pixel index, col = p-1)
                const int cph  = slot & 31;
                const int clog = cph ^ (p & 7);
                const int col  = p - 1;
                const bool v   = rowok && (col >= 0) && (col < W_);
                const void* src = v ? (const void*)(xrow + (size_t)col * CH_ + clog * 8)
                                    : (const void*)zglob;
                gll16(src, (char*)&xt[0] + e * 1024);
            }
        }
    };

    // ================= prologue =================
    stage_row(0);
    loadBh(0, 0, rgA);
    loadBh(0, 1, rgB);
    if (tid < 80) {                           // fold norm into raw sel
        float rv[9]; int cnt = 0;
        #pragma unroll
        for (int k = 0; k < 9; ++k) { rv[k] = ssel[k * NPIX + rt * W_ + tid]; cnt += (rv[k] != 0.f) ? 1 : 0; }
        const float norm = (cnt > 0) ? 9.f / (float)cnt : 0.f;
        #pragma unroll
        for (int k = 0; k < 9; ++k) sl[k][tid] = rv[k] * norm;
    }
    __syncthreads();                          // drains gll + B + sl

    // ================= main loop: 9 taps, barriers only at row swaps ========
    const floatx4 Z = {0.f, 0.f, 0.f, 0.f};
    const char* xbase = (const char*)&xt[0];

    for (int t = 0; t < 9; ++t) {             // tap k = t = 3i+j
        const int jj = t - (t / 3) * 3;
        const int pb = ln + jj;               // pixel = pb + im*16
        const int sw = pb & 7;

        floatx4 P[3][2];

        // ---- group 0: im 0..2 ----
        #pragma unroll
        for (int k2 = 0; k2 < 8; ++k2) {
            const int choff = ((((k2 << 2) | quad) ^ sw) << 4);
            short8 a0 = *(const short8*)(xbase + (size_t)(pb +  0) * 512 + choff);
            short8 a1 = *(const short8*)(xbase + (size_t)(pb + 16) * 512 + choff);
            short8 a2 = *(const short8*)(xbase + (size_t)(pb + 32) * 512 + choff);
            const short8 b0 = (k2 < 4) ? rgA[k2 * 2 + 0] : rgB[(k2 - 4) * 2 + 0];
            const short8 b1 = (k2 < 4) ? rgA[k2 * 2 + 1] : rgB[(k2 - 4) * 2 + 1];
            if (k2 == 0) {
                P[0][0] = __builtin_amdgcn_mfma_f32_16x16x32_bf16(a0, b0, Z, 0, 0, 0);
                P[0][1] = __builtin_amdgcn_mfma_f32_16x16x32_bf16(a0, b1, Z, 0, 0, 0);
                P[1][0] = __builtin_amdgcn_mfma_f32_16x16x32_bf16(a1, b0, Z, 0, 0, 0);
                P[1][1] = __builtin_amdgcn_mfma_f32_16x16x32_bf16(a1, b1, Z, 0, 0, 0);
                P[2][0] = __builtin_amdgcn_mfma_f32_16x16x32_bf16(a2, b0, Z, 0, 0, 0);
                P[2][1] = __builtin_amdgcn_mfma_f32_16x16x32_bf16(a2, b1, Z, 0, 0, 0);
            } else {
                P[0][0] = __builtin_amdgcn_mfma_f32_16x16x32_bf16(a0, b0, P[0][0], 0, 0, 0);
                P[0][1] = __builtin_amdgcn_mfma_f32_16x16x32_bf16(a0, b1, P[0][1], 0, 0, 0);
                P[1][0] = __builtin_amdgcn_mfma_f32_16x16x32_bf16(a1, b0, P[1][0], 0, 0, 0);
                P[1][1] = __builtin_amdgcn_mfma_f32_16x16x32_bf16(a1, b1, P[1][1], 0, 0, 0);
                P[2][0] = __builtin_amdgcn_mfma_f32_16x16x32_bf16(a2, b0, P[2][0], 0, 0, 0);
                P[2][1] = __builtin_amdgcn_mfma_f32_16x16x32_bf16(a2, b1, P[2][1], 0, 0, 0);
            }
        }
        #pragma unroll
        for (int im = 0; im < 3; ++im) {
            const float4 sv = *(const float4*)&sl[t][im * 16 + quad * 4];
            #pragma unroll
            for (int jn = 0; jn < 2; ++jn) {
                O[im][jn][0] += sv.x * P[im][jn][0];
                O[im][jn][1] += sv.y * P[im][jn][1];
                O[im][jn][2] += sv.z * P[im][jn][2];
                O[im][jn][3] += sv.w * P[im][jn][3];
            }
        }

        // ---- group 1: im 3..4 (rgA half, then refill rgA; rgB half, refill) --
        #pragma unroll
        for (int k2 = 0; k2 < 4; ++k2) {
            const int choff = ((((k2 << 2) | quad) ^ sw) << 4);
            short8 a3 = *(const short8*)(xbase + (size_t)(pb + 48) * 512 + choff);
            short8 a4 = *(const short8*)(xbase + (size_t)(pb + 64) * 512 + choff);
            if (k2 == 0) {
                P[0][0] = __builtin_amdgcn_mfma_f32_16x16x32_bf16(a3, rgA[0], Z, 0, 0, 0);
                P[0][1] = __builtin_amdgcn_mfma_f32_16x16x32_bf16(a3, rgA[1], Z, 0, 0, 0);
                P[1][0] = __builtin_amdgcn_mfma_f32_16x16x32_bf16(a4, rgA[0], Z, 0, 0, 0);
                P[1][1] = __builtin_amdgcn_mfma_f32_16x16x32_bf16(a4, rgA[1], Z, 0, 0, 0);
            } else {
                P[0][0] = __builtin_amdgcn_mfma_f32_16x16x32_bf16(a3, rgA[k2 * 2 + 0], P[0][0], 0, 0, 0);
                P[0][1] = __builtin_amdgcn_mfma_f32_16x16x32_bf16(a3, rgA[k2 * 2 + 1], P[0][1], 0, 0, 0);
                P[1][0] = __builtin_amdgcn_mfma_f32_16x16x32_bf16(a4, rgA[k2 * 2 + 0], P[1][0], 0, 0, 0);
                P[1][1] = __builtin_amdgcn_mfma_f32_16x16x32_bf16(a4, rgA[k2 * 2 + 1], P[1][1], 0, 0, 0);
            }
        }
        if (t < 8) loadBh(t + 1, 0, rgA);     // after rgA's last use
        #pragma unroll
        for (int k2 = 0; k2 < 4; ++k2) {
            const int choff = (((((k2 + 4) << 2) | quad) ^ sw) << 4);
            short8 a3 = *(const short8*)(xbase + (size_t)(pb + 48) * 512 + choff);
            short8 a4 = *(const short8*)(xbase + (size_t)(pb + 64) * 512 + choff);
            P[0][0] = __builtin_amdgcn_mfma_f32_16x16x32_bf16(a3, rgB[k2 * 2 + 0], P[0][0], 0, 0, 0);
            P[0][1] = __builtin_amdgcn_mfma_f32_16x16x32_bf16(a3, rgB[k2 * 2 + 1], P[0][1], 0, 0, 0);
            P[1][0] = __builtin_amdgcn_mfma_f32_16x16x32_bf16(a4, rgB[k2 * 2 + 0], P[1][0], 0, 0, 0);
            P[1][1] = __builtin_amdgcn_mfma_f32_16x16x32_bf16(a4, rgB[k2 * 2 + 1], P[1][1], 0, 0, 0);
        }
        if (t < 8) loadBh(t + 1, 1, rgB);     // after rgB's last use
        #pragma unroll
        for (int g = 0; g < 2; ++g) {
            const float4 sv = *(const float4*)&sl[t][(g + 3) * 16 + quad * 4];
            #pragma unroll
            for (int jn = 0; jn < 2; ++jn) {
                O[g + 3][jn][0] += sv.x * P[g][jn][0];
                O[g + 3][jn][1] += sv.y * P[g][jn][1];
                O[g + 3][jn][2] += sv.z * P[g][jn][2];
                O[g + 3][jn][3] += sv.w * P[g][jn][3];
            }
        }

        if (t == 2)      { __syncthreads(); stage_row(1); __syncthreads(); }
        else if (t == 5) { __syncthreads(); stage_row(2); __syncthreads(); }
    }

    // epilogue: C/D layout col(d)=lane&15, row(m)=quad*4+reg
    #pragma unroll
    for (int im = 0; im < 5; ++im) {
        #pragma unroll
        for (int jn = 0; jn < 2; ++jn) {
            const int dd = d0 + wv * 32 + jn * 16 + ln;
            #pragma unroll
            for (int r = 0; r < 4; ++r) {
                const int m = im * 16 + quad * 4 + r;
                out[((size_t)(rt * W_ + m)) * DIM_ + dd] = O[im][jn][r];
            }
        }
    }
}

// ---------------------------------------------------------------------------
// conv2_fb: r0-proven fp32-staging fallback (only if workspace too small for xb).
// ---------------------------------------------------------------------------
__global__ __launch_bounds__(256, 3) void conv2_fb(const float* __restrict__ x,
                                                   const float* __restrict__ ssel,
                                                   const ushort* __restrict__ wbT,
                                                   float* __restrict__ out)
{
    __shared__ ushort xsA[2][80 * 136];
    __shared__ float  sl[9][80];

    const int tid  = threadIdx.x;
    const int lane = tid & 63;
    const int wv   = tid >> 6;
    const int ln   = lane & 15;
    const int quad = lane >> 4;
    const int rt   = blockIdx.x;
    const int b    = rt / H_;
    const int h    = rt % H_;
    const int d0   = blockIdx.y * 128;

    int qm[5], qc[5];
    #pragma unroll
    for (int r = 0; r < 5; ++r) { int q = tid + 256 * r; qm[r] = q >> 4; qc[r] = q & 15; }

    floatx4 O[5][2];
    #pragma unroll
    for (int i = 0; i < 5; ++i)
        #pragma unroll
        for (int jn = 0; jn < 2; ++jn)
            O[i][jn] = (floatx4){0.f, 0.f, 0.f, 0.f};

    float4 fa[5], fb[5];
    bool   ok[5];

    auto stage_load = [&](int nit) {
        const int i = nit / 6, rem = nit % 6, cc = (rem / 3) * 128, jj = rem % 3;
        const int rr = h + i - 1;
        const bool rowok = (rr >= 0) && (rr < H_);
        const int rsafe = rowok ? rr : h;
        #pragma unroll
        for (int r = 0; r < 5; ++r) {
            const int col = qm[r] + jj - 1;
            const bool v = rowok && (col >= 0) && (col < W_);
            ok[r] = v;
            const float* f = x + ((size_t)(b * H_ + rsafe) * W_ + (v ? col : 0)) * CH_ + cc + qc[r] * 8;
            fa[r] = *(const float4*)f;
            fb[r] = *(const float4*)(f + 4);
        }
    };
    auto stage_write = [&](int nit) {
        ushort* bp = xsA[nit & 1];
        #pragma unroll
        for (int r = 0; r < 5; ++r) {
            uint4 v = ok[r] ? make_uint4(pk2(fa[r].x, fa[r].y), pk2(fa[r].z, fa[r].w),
                                         pk2(fb[r].x, fb[r].y), pk2(fb[r].z, fb[r].w))
                            : make_uint4(0u, 0u, 0u, 0u);
            *(uint4*)&bp[qm[r] * 136 + qc[r] * 8] = v;
        }
    };

    short8 Breg[8];
    auto loadB = [&](int nit) {
        const int i = nit / 6, rem = nit % 6, cc = (rem / 3) * 128, jj = rem % 3;
        const int k = 3 * i + jj;
        #pragma unroll
        for (int kk = 0; kk < 4; ++kk)
            #pragma unroll
            for (int jn = 0; jn < 2; ++jn)
                Breg[kk * 2 + jn] = *(const short8*)(wbT
                    + ((size_t)k * 256 + d0 + wv * 32 + jn * 16 + ln) * 256
                    + cc + kk * 32 + quad * 8);
    };

    stage_load(0);
    if (tid < 80) {
        float rv[9]; int cnt = 0;
        #pragma unroll
        for (int k = 0; k < 9; ++k) { rv[k] = ssel[k * NPIX + rt * W_ + tid]; cnt += (rv[k] != 0.f) ? 1 : 0; }
        const float norm = (cnt > 0) ? 9.f / (float)cnt : 0.f;
        #pragma unroll
        for (int k = 0; k < 9; ++k) sl[k][tid] = rv[k] * norm;
    }
    __syncthreads();
    stage_write(0);
    loadB(0);
    __syncthreads();

    #pragma unroll 2
    for (int it = 0; it < 18; ++it) {
        const int i = it / 6, rem = it % 6, jj = rem % 3;
        const int k = 3 * i + jj;
        const ushort* bp = xsA[it & 1];

        if (it < 17) stage_load(it + 1);

        floatx4 P[5][2];
        #pragma unroll
        for (int im = 0; im < 5; ++im)
            #pragma unroll
            for (int jn = 0; jn < 2; ++jn)
                P[im][jn] = (floatx4){0.f, 0.f, 0.f, 0.f};

        #pragma unroll
        for (int kk = 0; kk < 4; ++kk) {
            short8 a[5];
            #pragma unroll
            for (int im = 0; im < 5; ++im)
                a[im] = *(const short8*)&bp[(im * 16 + ln) * 136 + kk * 32 + quad * 8];
            #pragma unroll
            for (int im = 0; im < 5; ++im)
                #pragma unroll
                for (int jn = 0; jn < 2; ++jn)
                    P[im][jn] = __builtin_amdgcn_mfma_f32_16x16x32_bf16(
                        a[im], Breg[kk * 2 + jn], P[im][jn], 0, 0, 0);
        }

        if (it < 17) stage_write(it + 1);
        if (it < 17) loadB(it + 1);

        #pragma unroll
        for (int im = 0; im < 5; ++im) {
            const float4 sv = *(const float4*)&sl[k][im * 16 + quad * 4];
            #pragma unroll
            for (int jn = 0; jn < 2; ++jn) {
                O[im][jn][0] += sv.x * P[im][jn][0];
                O[im][jn][1] += sv.y * P[im][jn][1];
                O[im][jn][2] += sv.z * P[im][jn][2];
                O[im][jn][3] += sv.w * P[im][jn][3];
            }
        }
        __syncthreads();
    }

    #pragma unroll
    for (int im = 0; im < 5; ++im)
        #pragma unroll
        for (int jn = 0; jn < 2; ++jn) {
            const int dd = d0 + wv * 32 + jn * 16 + ln;
            #pragma unroll
            for (int r = 0; r < 4; ++r) {
                const int m = im * 16 + quad * 4 + r;
                out[((size_t)(rt * W_ + m)) * DIM_ + dd] = O[im][jn][r];
            }
        }
}

extern "C" void kernel_launch(void* const* d_in, const int* in_sizes, int n_in,
                              void* d_out, int out_size, void* d_ws, size_t ws_size,
                              hipStream_t stream)
{
    const float* x   = (const float*)d_in[0];   // (4,80,80,256) f32
    const float* seg = (const float*)d_in[1];   // (4,80,80,22)  f32
    const float* cw  = (const float*)d_in[2];   // (256,3,3,256) f32
    float* out = (float*)d_out;

    float*  ssel = (float*)d_ws;                                   // 921600 B (raw)
    ushort* wbT  = (ushort*)((char*)d_ws + 921600);                // 1179648 B
    ushort* xb   = (ushort*)((char*)d_ws + 921600 + 1179648);      // 13107200 B
    const size_t need = 921600u + 1179648u + 13107200u;

    prep<<<dim3(900 + 72), dim3(256), 0, stream>>>(seg, cw, ssel, wbT);

    if (ws_size >= need) {
        cvt_x<<<dim3(NPIX * CH_ / (256 * 8)), dim3(256), 0, stream>>>(x, xb);
        conv2<<<dim3(B_ * H_, 2), dim3(256), 0, stream>>>(xb, ssel, wbT, out);
    } else {
        conv2_fb<<<dim3(B_ * H_, 2), dim3(256), 0, stream>>>(x, ssel, wbT, out);
    }
}

// Round 6
// 156.380 us; speedup vs baseline: 1.6933x; 1.6933x over previous
//
#include <hip/hip_runtime.h>
#include <hip/hip_bf16.h>
#include <cstdint>

#define B_ 4
#define H_ 80
#define W_ 80
#define CH_ 256
#define NC_ 22
#define DIM_ 256
#define NPIX (B_*H_*W_)

typedef unsigned short ushort;
typedef __attribute__((ext_vector_type(8))) short short8;     // 8 bf16 = 4 VGPR
typedef __attribute__((ext_vector_type(4))) float floatx4;    // MFMA C/D frag

static __device__ inline ushort f2bf(float v) {
    __hip_bfloat16 h = __float2bfloat16(v);   // RNE
    ushort r;
    __builtin_memcpy(&r, &h, 2);
    return r;
}
static __device__ inline unsigned pk2(float a, float b) {
    return (unsigned)f2bf(a) | ((unsigned)f2bf(b) << 16);
}

// ---------------------------------------------------------------------------
// prep: ONE launch fusing three independent jobs, branched on blockIdx.x:
//   [0,900):      raw sel, (m,k)-parallel (t = k*NPIX + m), 24 loads/thread
//   [900,972):    weight repack cw[c][k][d] f32 -> wbT[k][d][c] bf16
//   [972,4172):   cvt_x: x f32 -> xb bf16 (8 elems/thread)
// All three bodies are individually proven (r1/r4/r5 pass).
// ---------------------------------------------------------------------------
__global__ __launch_bounds__(256) void prep(const float* __restrict__ seg,
                                            const float* __restrict__ cw,
                                            const float* __restrict__ x,
                                            float* __restrict__ ssel,
                                            ushort* __restrict__ wbT,
                                            ushort* __restrict__ xb)
{
    __shared__ ushort ls[32][260];
    if (blockIdx.x < 900) {
        const int t = blockIdx.x * 256 + threadIdx.x;     // = k*NPIX + m
        const int k = t / NPIX;
        const int m = t - k * NPIX;
        const int w = m % W_;
        const int h = (m / W_) % H_;
        const int b = m / (W_ * H_);

        const float2* c2 = (const float2*)(seg + (size_t)m * NC_);
        float cv[NC_];
        #pragma unroll
        for (int c = 0; c < NC_ / 2; ++c) { float2 v = c2[c]; cv[2*c] = v.x; cv[2*c+1] = v.y; }
        float mx = -1e30f;
        #pragma unroll
        for (int c = 0; c < NC_; ++c) mx = fmaxf(mx, cv[c]);

        const int i = k / 3, j = k % 3;
        const int hh = h + i - 1, ww = w + j - 1;
        float s = 0.f;
        if (hh >= 0 && hh < H_ && ww >= 0 && ww < W_) {
            const float2* n2 = (const float2*)(seg + ((size_t)((b * H_ + hh) * W_ + ww)) * NC_);
            #pragma unroll
            for (int c = 0; c < NC_ / 2; ++c) {
                float2 v = n2[c];
                s += (cv[2*c]   == mx) ? v.x : 0.f;
                s += (cv[2*c+1] == mx) ? v.y : 0.f;
            }
        }
        ssel[t] = s;                                      // RAW sel (norm in conv2)
    } else if (blockIdx.x < 972) {
        const int bx = blockIdx.x - 900;
        const int k  = bx / 8;
        const int c0 = (bx % 8) * 32;
        const int c    = threadIdx.x >> 3;                // 0..31
        const int seg8 = threadIdx.x & 7;                 // 0..7

        const float* src = cw + ((size_t)(c0 + c) * 9 + k) * DIM_ + seg8 * 32;
        #pragma unroll
        for (int e = 0; e < 32; e += 4) {
            float4 v = *(const float4*)(src + e);
            unsigned* dst = (unsigned*)&ls[c][seg8 * 32 + e];
            dst[0] = pk2(v.x, v.y);
            dst[1] = pk2(v.z, v.w);
        }
        __syncthreads();

        const int d = threadIdx.x;                        // 0..255
        ushort tmp[32];
        #pragma unroll
        for (int cc = 0; cc < 32; ++cc) tmp[cc] = ls[cc][d];
        uint4 o[4];
        __builtin_memcpy(o, tmp, 64);
        uint4* dst = (uint4*)(wbT + ((size_t)k * 256 + d) * 256 + c0);
        dst[0] = o[0]; dst[1] = o[1]; dst[2] = o[2]; dst[3] = o[3];
    } else if (xb != nullptr) {
        size_t idx = ((size_t)(blockIdx.x - 972) * 256 + threadIdx.x) * 8;
        const float4* s = (const float4*)(x + idx);
        float4 a = s[0], b = s[1];
        uint4 o = make_uint4(pk2(a.x, a.y), pk2(a.z, a.w), pk2(b.x, b.y), pk2(b.z, b.w));
        *(uint4*)(xb + idx) = o;
    }
}

// ---------------------------------------------------------------------------
// conv2: taps-outer implicit GEMM — PROVEN round-0 structure (77.5 us),
// main loop byte-identical. Block = row (M=80) x 128 d, 4 waves. Interval
// it in [0,18): i=it/6, cc=((it%6)/3)*128, j=it%3, tap k=3i+j.
// P (fresh) += A*B over 4 kk; then O += sl_k[m]*P (f32 on C-frag).
// A: LDS double-buffered (rows padded to 136 ush). B: global->reg, loaded
// AFTER last use, consumed only after barrier. One barrier per interval.
// Only change vs r0: sl prologue folds norm from RAW ssel (80 thr x 9 loads).
// ---------------------------------------------------------------------------
template<bool XB16>
__global__ __launch_bounds__(256, 3) void conv2(const float* __restrict__ x,
                                                const ushort* __restrict__ xb,
                                                const float* __restrict__ ssel,
                                                const ushort* __restrict__ wbT,
                                                float* __restrict__ out)
{
    __shared__ ushort xsA[2][80 * 136];      // 43.5 KB
    __shared__ float  sl[9][80];             // 2.8 KB

    const int tid  = threadIdx.x;
    const int lane = tid & 63;
    const int wv   = tid >> 6;               // d-offset wv*32
    const int ln   = lane & 15;
    const int quad = lane >> 4;
    const int rt   = blockIdx.x;             // b*H + h
    const int b    = rt / H_;
    const int h    = rt % H_;
    const int d0   = blockIdx.y * 128;

    // per-thread staging chunk constants: q = tid + 256*r -> (pixel m, 16B block cb)
    int qm[5], qc[5];
    #pragma unroll
    for (int r = 0; r < 5; ++r) {
        int q = tid + 256 * r;
        qm[r] = q >> 4;
        qc[r] = q & 15;
    }

    floatx4 O[5][2];
    #pragma unroll
    for (int i = 0; i < 5; ++i)
        #pragma unroll
        for (int jn = 0; jn < 2; ++jn)
            O[i][jn] = (floatx4){0.f, 0.f, 0.f, 0.f};

    // staging pipeline registers
    uint4  sg[5];                    // bf16 path
    float4 fa[5], fb[5];             // fp32 path
    bool   ok[5];

    auto stage_load = [&](int nit) {
        const int i   = nit / 6;
        const int rem = nit % 6;
        const int cc  = (rem / 3) * 128;
        const int jj  = rem % 3;
        const int rr  = h + i - 1;
        const bool rowok = (rr >= 0) && (rr < H_);
        const int rsafe = rowok ? rr : h;
        #pragma unroll
        for (int r = 0; r < 5; ++r) {
            const int col = qm[r] + jj - 1;
            const bool v = rowok && (col >= 0) && (col < W_);
            ok[r] = v;
            const size_t gp = ((size_t)(b * H_ + rsafe) * W_ + (v ? col : 0));
            if (XB16) {
                sg[r] = *(const uint4*)(xb + gp * CH_ + cc + qc[r] * 8);
            } else {
                const float* f = x + gp * CH_ + cc + qc[r] * 8;
                fa[r] = *(const float4*)f;
                fb[r] = *(const float4*)(f + 4);
            }
        }
    };
    auto stage_write = [&](int nit) {
        ushort* bp = xsA[nit & 1];
        #pragma unroll
        for (int r = 0; r < 5; ++r) {
            uint4 v;
            if (XB16) {
                v = ok[r] ? sg[r] : make_uint4(0u, 0u, 0u, 0u);
            } else {
                v = ok[r] ? make_uint4(pk2(fa[r].x, fa[r].y), pk2(fa[r].z, fa[r].w),
                                       pk2(fb[r].x, fb[r].y), pk2(fb[r].z, fb[r].w))
                          : make_uint4(0u, 0u, 0u, 0u);
            }
            *(uint4*)&bp[qm[r] * 136 + qc[r] * 8] = v;
        }
    };

    short8 Breg[8];                  // [kk][jn] for current interval
    auto loadB = [&](int nit) {
        const int i   = nit / 6;
        const int rem = nit % 6;
        const int cc  = (rem / 3) * 128;
        const int jj  = rem % 3;
        const int k   = 3 * i + jj;
        #pragma unroll
        for (int kk = 0; kk < 4; ++kk)
            #pragma unroll
            for (int jn = 0; jn < 2; ++jn)
                Breg[kk * 2 + jn] = *(const short8*)(wbT
                    + ((size_t)k * 256 + d0 + wv * 32 + jn * 16 + ln) * 256
                    + cc + kk * 32 + quad * 8);
    };

    // prologue: x loads first (fly during sl fold), then fold norm into sl
    stage_load(0);
    if (tid < 80) {
        float rv[9]; int cnt = 0;
        #pragma unroll
        for (int k = 0; k < 9; ++k) {
            rv[k] = ssel[k * NPIX + rt * W_ + tid];
            cnt += (rv[k] != 0.f) ? 1 : 0;
        }
        const float norm = (cnt > 0) ? 9.f / (float)cnt : 0.f;
        #pragma unroll
        for (int k = 0; k < 9; ++k) sl[k][tid] = rv[k] * norm;
    }
    stage_write(0);
    loadB(0);
    __syncthreads();                          // sl + buf0 ready, B drained

    #pragma unroll 2
    for (int it = 0; it < 18; ++it) {
        const int i   = it / 6;
        const int rem = it % 6;
        const int jj  = rem % 3;
        const int k   = 3 * i + jj;
        const ushort* bp = xsA[it & 1];

        if (it < 17) stage_load(it + 1);     // globals in flight during MFMA

        floatx4 P[5][2];
        #pragma unroll
        for (int im = 0; im < 5; ++im)
            #pragma unroll
            for (int jn = 0; jn < 2; ++jn)
                P[im][jn] = (floatx4){0.f, 0.f, 0.f, 0.f};

        #pragma unroll
        for (int kk = 0; kk < 4; ++kk) {
            short8 a[5];
            #pragma unroll
            for (int im = 0; im < 5; ++im)
                a[im] = *(const short8*)&bp[(im * 16 + ln) * 136 + kk * 32 + quad * 8];
            #pragma unroll
            for (int im = 0; im < 5; ++im)
                #pragma unroll
                for (int jn = 0; jn < 2; ++jn)
                    P[im][jn] = __builtin_amdgcn_mfma_f32_16x16x32_bf16(
                        a[im], Breg[kk * 2 + jn], P[im][jn], 0, 0, 0);
        }

        if (it < 17) stage_write(it + 1);    // vmcnt wait lands after MFMA
        if (it < 17) loadB(it + 1);          // B for next interval in flight

        // scale-accumulate: O += s_k[m] * P  (row m = im*16 + quad*4 + r)
        #pragma unroll
        for (int im = 0; im < 5; ++im) {
            const float4 sv = *(const float4*)&sl[k][im * 16 + quad * 4];
            #pragma unroll
            for (int jn = 0; jn < 2; ++jn) {
                O[im][jn][0] += sv.x * P[im][jn][0];
                O[im][jn][1] += sv.y * P[im][jn][1];
                O[im][jn][2] += sv.z * P[im][jn][2];
                O[im][jn][3] += sv.w * P[im][jn][3];
            }
        }
        __syncthreads();
    }

    // epilogue: C/D layout col(d)=lane&15, row(m)=quad*4+reg
    #pragma unroll
    for (int im = 0; im < 5; ++im) {
        #pragma unroll
        for (int jn = 0; jn < 2; ++jn) {
            const int dd = d0 + wv * 32 + jn * 16 + ln;
            #pragma unroll
            for (int r = 0; r < 4; ++r) {
                const int m = im * 16 + quad * 4 + r;
                out[((size_t)(rt * W_ + m)) * DIM_ + dd] = O[im][jn][r];
            }
        }
    }
}

extern "C" void kernel_launch(void* const* d_in, const int* in_sizes, int n_in,
                              void* d_out, int out_size, void* d_ws, size_t ws_size,
                              hipStream_t stream)
{
    const float* x   = (const float*)d_in[0];   // (4,80,80,256) f32
    const float* seg = (const float*)d_in[1];   // (4,80,80,22)  f32
    const float* cw  = (const float*)d_in[2];   // (256,3,3,256) f32
    float* out = (float*)d_out;

    float*  ssel = (float*)d_ws;                                   // 921600 B (raw)
    ushort* wbT  = (ushort*)((char*)d_ws + 921600);                // 1179648 B
    ushort* xb   = (ushort*)((char*)d_ws + 921600 + 1179648);      // 13107200 B
    const size_t need = 921600u + 1179648u + 13107200u;

    if (ws_size >= need) {
        prep<<<dim3(972 + 3200), dim3(256), 0, stream>>>(seg, cw, x, ssel, wbT, xb);
        conv2<true><<<dim3(B_ * H_, 2), dim3(256), 0, stream>>>(x, xb, ssel, wbT, out);
    } else {
        prep<<<dim3(972), dim3(256), 0, stream>>>(seg, cw, x, ssel, wbT, nullptr);
        conv2<false><<<dim3(B_ * H_, 2), dim3(256), 0, stream>>>(x, nullptr, ssel, wbT, out);
    }
}

// Round 7
// 149.355 us; speedup vs baseline: 1.7730x; 1.0470x over previous
//
#include <hip/hip_runtime.h>
#include <hip/hip_bf16.h>
#include <cstdint>

#define B_ 4
#define H_ 80
#define W_ 80
#define CH_ 256
#define NC_ 22
#define DIM_ 256
#define NPIX (B_*H_*W_)

typedef unsigned short ushort;
typedef __attribute__((ext_vector_type(8))) short short8;     // 8 bf16 = 4 VGPR
typedef __attribute__((ext_vector_type(4))) float floatx4;    // MFMA C/D frag

__device__ __attribute__((aligned(256))) static const unsigned char zglob[256] = {};

static __device__ inline ushort f2bf(float v) {
    __hip_bfloat16 h = __float2bfloat16(v);   // RNE
    ushort r;
    __builtin_memcpy(&r, &h, 2);
    return r;
}
static __device__ inline unsigned pk2(float a, float b) {
    return (unsigned)f2bf(a) | ((unsigned)f2bf(b) << 16);
}
static __device__ inline void gll16(const void* g, void* l) {
    __builtin_amdgcn_global_load_lds((const __attribute__((address_space(1))) void*)g,
                                     (__attribute__((address_space(3))) void*)l, 16, 0, 0);
}

// ---------------------------------------------------------------------------
// prep: ONE launch fusing three independent jobs (r6-proven, byte-identical):
//   [0,900):      raw sel, (m,k)-parallel (t = k*NPIX + m)
//   [900,972):    weight repack cw[c][k][d] f32 -> wbT[k][d][c] bf16
//   [972,4172):   cvt_x: x f32 -> xb bf16 (8 elems/thread)
// ---------------------------------------------------------------------------
__global__ __launch_bounds__(256) void prep(const float* __restrict__ seg,
                                            const float* __restrict__ cw,
                                            const float* __restrict__ x,
                                            float* __restrict__ ssel,
                                            ushort* __restrict__ wbT,
                                            ushort* __restrict__ xb)
{
    __shared__ ushort ls[32][260];
    if (blockIdx.x < 900) {
        const int t = blockIdx.x * 256 + threadIdx.x;     // = k*NPIX + m
        const int k = t / NPIX;
        const int m = t - k * NPIX;
        const int w = m % W_;
        const int h = (m / W_) % H_;
        const int b = m / (W_ * H_);

        const float2* c2 = (const float2*)(seg + (size_t)m * NC_);
        float cv[NC_];
        #pragma unroll
        for (int c = 0; c < NC_ / 2; ++c) { float2 v = c2[c]; cv[2*c] = v.x; cv[2*c+1] = v.y; }
        float mx = -1e30f;
        #pragma unroll
        for (int c = 0; c < NC_; ++c) mx = fmaxf(mx, cv[c]);

        const int i = k / 3, j = k % 3;
        const int hh = h + i - 1, ww = w + j - 1;
        float s = 0.f;
        if (hh >= 0 && hh < H_ && ww >= 0 && ww < W_) {
            const float2* n2 = (const float2*)(seg + ((size_t)((b * H_ + hh) * W_ + ww)) * NC_);
            #pragma unroll
            for (int c = 0; c < NC_ / 2; ++c) {
                float2 v = n2[c];
                s += (cv[2*c]   == mx) ? v.x : 0.f;
                s += (cv[2*c+1] == mx) ? v.y : 0.f;
            }
        }
        ssel[t] = s;                                      // RAW sel (norm in conv2)
    } else if (blockIdx.x < 972) {
        const int bx = blockIdx.x - 900;
        const int k  = bx / 8;
        const int c0 = (bx % 8) * 32;
        const int c    = threadIdx.x >> 3;                // 0..31
        const int seg8 = threadIdx.x & 7;                 // 0..7

        const float* src = cw + ((size_t)(c0 + c) * 9 + k) * DIM_ + seg8 * 32;
        #pragma unroll
        for (int e = 0; e < 32; e += 4) {
            float4 v = *(const float4*)(src + e);
            unsigned* dst = (unsigned*)&ls[c][seg8 * 32 + e];
            dst[0] = pk2(v.x, v.y);
            dst[1] = pk2(v.z, v.w);
        }
        __syncthreads();

        const int d = threadIdx.x;                        // 0..255
        ushort tmp[32];
        #pragma unroll
        for (int cc = 0; cc < 32; ++cc) tmp[cc] = ls[cc][d];
        uint4 o[4];
        __builtin_memcpy(o, tmp, 64);
        uint4* dst = (uint4*)(wbT + ((size_t)k * 256 + d) * 256 + c0);
        dst[0] = o[0]; dst[1] = o[1]; dst[2] = o[2]; dst[3] = o[3];
    } else if (xb != nullptr) {
        size_t idx = ((size_t)(blockIdx.x - 972) * 256 + threadIdx.x) * 8;
        const float4* s = (const float4*)(x + idx);
        float4 a = s[0], b = s[1];
        uint4 o = make_uint4(pk2(a.x, a.y), pk2(a.z, a.w), pk2(b.x, b.y), pk2(b.z, b.w));
        *(uint4*)(xb + idx) = o;
    }
}

// ---------------------------------------------------------------------------
// conv2: r6 loop (P-per-tap, im=5/jn=2, Breg[8], 18 intervals, 1 barrier each)
// with staging replaced by DIRECT global_load_lds (r5-verified addressing):
//   per interval, 1280x16B chunks; LDS tile 80px x 128ch LINEAR rows (256B),
//   chunk swizzle c_stored = c ^ (p&7): inverse-swizzled gll SOURCE +
//   swizzled A-read -> conflict-free ds_read_b128, no reg round-trip,
//   no ds_write, no pack VALU. Barrier drains only top-of-interval VMEM.
// ---------------------------------------------------------------------------
__global__ __launch_bounds__(256, 3) void conv2(const ushort* __restrict__ xb,
                                                const float* __restrict__ ssel,
                                                const ushort* __restrict__ wbT,
                                                float* __restrict__ out)
{
    __shared__ __attribute__((aligned(1024))) ushort xs[2][80 * 128];  // 40 KB
    __shared__ float sl[9][80];                                        // 2.8 KB

    const int tid  = threadIdx.x;
    const int lane = tid & 63;
    const int wv   = tid >> 6;               // d-offset wv*32
    const int ln   = lane & 15;
    const int quad = lane >> 4;
    const int rt   = blockIdx.x;             // b*H + h
    const int b    = rt / H_;
    const int h    = rt % H_;
    const int d0   = blockIdx.y * 128;

    floatx4 O[5][2];
    #pragma unroll
    for (int i = 0; i < 5; ++i)
        #pragma unroll
        for (int jn = 0; jn < 2; ++jn)
            O[i][jn] = (floatx4){0.f, 0.f, 0.f, 0.f};

    short8 Breg[8];                  // [kk][jn] for current interval (32 VGPR)
    auto loadB = [&](int nit) {
        const int i   = nit / 6;
        const int rem = nit % 6;
        const int cc  = (rem / 3) * 128;
        const int jj  = rem % 3;
        const int k   = 3 * i + jj;
        #pragma unroll
        for (int kk = 0; kk < 4; ++kk)
            #pragma unroll
            for (int jn = 0; jn < 2; ++jn)
                Breg[kk * 2 + jn] = *(const short8*)(wbT
                    + ((size_t)k * 256 + d0 + wv * 32 + jn * 16 + ln) * 256
                    + cc + kk * 32 + quad * 8);
    };

    // stage interval nit into xs[nit&1] via global_load_lds.
    // slot s in [0,1280): pixel p = s>>4, stored-chunk cph = s&15 holds
    // global chunk clog = cph ^ (p&7)  (involution; read applies same XOR).
    auto stage = [&](int nit) {
        const int i   = nit / 6;
        const int rem = nit % 6;
        const int cc  = (rem / 3) * 128;
        const int jj  = rem % 3;
        const int rr  = h + i - 1;
        const bool rowok = (rr >= 0) && (rr < H_);
        const ushort* xrow = xb + ((size_t)((b * H_ + (rowok ? rr : 0)) * W_)) * CH_ + cc;
        char* dbase = (char*)&xs[nit & 1][0];
        #pragma unroll
        for (int r = 0; r < 5; ++r) {
            const int s    = (r * 4 + wv) * 64 + lane;
            const int p    = s >> 4;
            const int cph  = s & 15;
            const int clog = cph ^ (p & 7);
            const int col  = p + jj - 1;
            const bool v   = rowok && (col >= 0) && (col < W_);
            const void* src = v ? (const void*)(xrow + (size_t)col * CH_ + clog * 8)
                                : (const void*)zglob;
            gll16(src, dbase + (size_t)(r * 4 + wv) * 1024);
        }
    };

    // ================= prologue =================
    stage(0);
    loadB(0);
    if (tid < 80) {                           // fold norm into raw sel
        float rv[9]; int cnt = 0;
        #pragma unroll
        for (int k = 0; k < 9; ++k) {
            rv[k] = ssel[k * NPIX + rt * W_ + tid];
            cnt += (rv[k] != 0.f) ? 1 : 0;
        }
        const float norm = (cnt > 0) ? 9.f / (float)cnt : 0.f;
        #pragma unroll
        for (int k = 0; k < 9; ++k) sl[k][tid] = rv[k] * norm;
    }
    __syncthreads();                          // buf0 + Breg + sl ready

    // ================= main loop =================
    #pragma unroll 2
    for (int it = 0; it < 18; ++it) {
        const int i   = it / 6;
        const int rem = it % 6;
        const int jj  = rem % 3;
        const int k   = 3 * i + jj;
        const char* bp = (const char*)&xs[it & 1][0];

        if (it < 17) stage(it + 1);          // 5 gll, no dependents, drain at bar

        floatx4 P[5][2];
        #pragma unroll
        for (int im = 0; im < 5; ++im)
            #pragma unroll
            for (int jn = 0; jn < 2; ++jn)
                P[im][jn] = (floatx4){0.f, 0.f, 0.f, 0.f};

        #pragma unroll
        for (int kk = 0; kk < 4; ++kk) {
            short8 a[5];
            #pragma unroll
            for (int im = 0; im < 5; ++im)
                a[im] = *(const short8*)(bp
                    + (size_t)(im * 16 + ln) * 256
                    + ((((kk << 2) | quad) ^ (ln & 7)) << 4));
            #pragma unroll
            for (int im = 0; im < 5; ++im)
                #pragma unroll
                for (int jn = 0; jn < 2; ++jn)
                    P[im][jn] = __builtin_amdgcn_mfma_f32_16x16x32_bf16(
                        a[im], Breg[kk * 2 + jn], P[im][jn], 0, 0, 0);
        }

        if (it < 17) loadB(it + 1);          // after last Breg use; used after bar

        // scale-accumulate: O += s_k[m] * P  (row m = im*16 + quad*4 + r)
        #pragma unroll
        for (int im = 0; im < 5; ++im) {
            const float4 sv = *(const float4*)&sl[k][im * 16 + quad * 4];
            #pragma unroll
            for (int jn = 0; jn < 2; ++jn) {
                O[im][jn][0] += sv.x * P[im][jn][0];
                O[im][jn][1] += sv.y * P[im][jn][1];
                O[im][jn][2] += sv.z * P[im][jn][2];
                O[im][jn][3] += sv.w * P[im][jn][3];
            }
        }
        __syncthreads();
    }

    // epilogue: C/D layout col(d)=lane&15, row(m)=quad*4+reg
    #pragma unroll
    for (int im = 0; im < 5; ++im) {
        #pragma unroll
        for (int jn = 0; jn < 2; ++jn) {
            const int dd = d0 + wv * 32 + jn * 16 + ln;
            #pragma unroll
            for (int r = 0; r < 4; ++r) {
                const int m = im * 16 + quad * 4 + r;
                out[((size_t)(rt * W_ + m)) * DIM_ + dd] = O[im][jn][r];
            }
        }
    }
}

// ---------------------------------------------------------------------------
// conv2_fb: r6-proven fp32 reg-staging fallback (workspace too small for xb).
// ---------------------------------------------------------------------------
__global__ __launch_bounds__(256, 3) void conv2_fb(const float* __restrict__ x,
                                                   const float* __restrict__ ssel,
                                                   const ushort* __restrict__ wbT,
                                                   float* __restrict__ out)
{
    __shared__ ushort xsA[2][80 * 136];
    __shared__ float  sl[9][80];

    const int tid  = threadIdx.x;
    const int lane = tid & 63;
    const int wv   = tid >> 6;
    const int ln   = lane & 15;
    const int quad = lane >> 4;
    const int rt   = blockIdx.x;
    const int b    = rt / H_;
    const int h    = rt % H_;
    const int d0   = blockIdx.y * 128;

    int qm[5], qc[5];
    #pragma unroll
    for (int r = 0; r < 5; ++r) { int q = tid + 256 * r; qm[r] = q >> 4; qc[r] = q & 15; }

    floatx4 O[5][2];
    #pragma unroll
    for (int i = 0; i < 5; ++i)
        #pragma unroll
        for (int jn = 0; jn < 2; ++jn)
            O[i][jn] = (floatx4){0.f, 0.f, 0.f, 0.f};

    float4 fa[5], fb[5];
    bool   ok[5];

    auto stage_load = [&](int nit) {
        const int i = nit / 6, rem = nit % 6, cc = (rem / 3) * 128, jj = rem % 3;
        const int rr = h + i - 1;
        const bool rowok = (rr >= 0) && (rr < H_);
        const int rsafe = rowok ? rr : h;
        #pragma unroll
        for (int r = 0; r < 5; ++r) {
            const int col = qm[r] + jj - 1;
            const bool v = rowok && (col >= 0) && (col < W_);
            ok[r] = v;
            const float* f = x + ((size_t)(b * H_ + rsafe) * W_ + (v ? col : 0)) * CH_ + cc + qc[r] * 8;
            fa[r] = *(const float4*)f;
            fb[r] = *(const float4*)(f + 4);
        }
    };
    auto stage_write = [&](int nit) {
        ushort* bp = xsA[nit & 1];
        #pragma unroll
        for (int r = 0; r < 5; ++r) {
            uint4 v = ok[r] ? make_uint4(pk2(fa[r].x, fa[r].y), pk2(fa[r].z, fa[r].w),
                                         pk2(fb[r].x, fb[r].y), pk2(fb[r].z, fb[r].w))
                            : make_uint4(0u, 0u, 0u, 0u);
            *(uint4*)&bp[qm[r] * 136 + qc[r] * 8] = v;
        }
    };

    short8 Breg[8];
    auto loadB = [&](int nit) {
        const int i = nit / 6, rem = nit % 6, cc = (rem / 3) * 128, jj = rem % 3;
        const int k = 3 * i + jj;
        #pragma unroll
        for (int kk = 0; kk < 4; ++kk)
            #pragma unroll
            for (int jn = 0; jn < 2; ++jn)
                Breg[kk * 2 + jn] = *(const short8*)(wbT
                    + ((size_t)k * 256 + d0 + wv * 32 + jn * 16 + ln) * 256
                    + cc + kk * 32 + quad * 8);
    };

    stage_load(0);
    if (tid < 80) {
        float rv[9]; int cnt = 0;
        #pragma unroll
        for (int k = 0; k < 9; ++k) { rv[k] = ssel[k * NPIX + rt * W_ + tid]; cnt += (rv[k] != 0.f) ? 1 : 0; }
        const float norm = (cnt > 0) ? 9.f / (float)cnt : 0.f;
        #pragma unroll
        for (int k = 0; k < 9; ++k) sl[k][tid] = rv[k] * norm;
    }
    stage_write(0);
    loadB(0);
    __syncthreads();

    #pragma unroll 2
    for (int it = 0; it < 18; ++it) {
        const int i = it / 6, rem = it % 6, jj = rem % 3;
        const int k = 3 * i + jj;
        const ushort* bp = xsA[it & 1];

        if (it < 17) stage_load(it + 1);

        floatx4 P[5][2];
        #pragma unroll
        for (int im = 0; im < 5; ++im)
            #pragma unroll
            for (int jn = 0; jn < 2; ++jn)
                P[im][jn] = (floatx4){0.f, 0.f, 0.f, 0.f};

        #pragma unroll
        for (int kk = 0; kk < 4; ++kk) {
            short8 a[5];
            #pragma unroll
            for (int im = 0; im < 5; ++im)
                a[im] = *(const short8*)&bp[(im * 16 + ln) * 136 + kk * 32 + quad * 8];
            #pragma unroll
            for (int im = 0; im < 5; ++im)
                #pragma unroll
                for (int jn = 0; jn < 2; ++jn)
                    P[im][jn] = __builtin_amdgcn_mfma_f32_16x16x32_bf16(
                        a[im], Breg[kk * 2 + jn], P[im][jn], 0, 0, 0);
        }

        if (it < 17) stage_write(it + 1);
        if (it < 17) loadB(it + 1);

        #pragma unroll
        for (int im = 0; im < 5; ++im) {
            const float4 sv = *(const float4*)&sl[k][im * 16 + quad * 4];
            #pragma unroll
            for (int jn = 0; jn < 2; ++jn) {
                O[im][jn][0] += sv.x * P[im][jn][0];
                O[im][jn][1] += sv.y * P[im][jn][1];
                O[im][jn][2] += sv.z * P[im][jn][2];
                O[im][jn][3] += sv.w * P[im][jn][3];
            }
        }
        __syncthreads();
    }

    #pragma unroll
    for (int im = 0; im < 5; ++im)
        #pragma unroll
        for (int jn = 0; jn < 2; ++jn) {
            const int dd = d0 + wv * 32 + jn * 16 + ln;
            #pragma unroll
            for (int r = 0; r < 4; ++r) {
                const int m = im * 16 + quad * 4 + r;
                out[((size_t)(rt * W_ + m)) * DIM_ + dd] = O[im][jn][r];
            }
        }
}

extern "C" void kernel_launch(void* const* d_in, const int* in_sizes, int n_in,
                              void* d_out, int out_size, void* d_ws, size_t ws_size,
                              hipStream_t stream)
{
    const float* x   = (const float*)d_in[0];   // (4,80,80,256) f32
    const float* seg = (const float*)d_in[1];   // (4,80,80,22)  f32
    const float* cw  = (const float*)d_in[2];   // (256,3,3,256) f32
    float* out = (float*)d_out;

    float*  ssel = (float*)d_ws;                                   // 921600 B (raw)
    ushort* wbT  = (ushort*)((char*)d_ws + 921600);                // 1179648 B
    ushort* xb   = (ushort*)((char*)d_ws + 921600 + 1179648);      // 13107200 B
    const size_t need = 921600u + 1179648u + 13107200u;

    if (ws_size >= need) {
        prep<<<dim3(972 + 3200), dim3(256), 0, stream>>>(seg, cw, x, ssel, wbT, xb);
        conv2<<<dim3(B_ * H_, 2), dim3(256), 0, stream>>>(xb, ssel, wbT, out);
    } else {
        prep<<<dim3(972), dim3(256), 0, stream>>>(seg, cw, x, ssel, wbT, nullptr);
        conv2_fb<<<dim3(B_ * H_, 2), dim3(256), 0, stream>>>(x, ssel, wbT, out);
    }
}